// Round 12
// baseline (197.608 us; speedup 1.0000x reference)
//
#include <hip/hip_runtime.h>

typedef unsigned short u16;
typedef __attribute__((ext_vector_type(8))) short bf16x8;
typedef __attribute__((ext_vector_type(4))) float f32x4;
typedef __attribute__((ext_vector_type(16))) float f32x16;
typedef __attribute__((ext_vector_type(4))) unsigned u32x4;

#define MFMA16 __builtin_amdgcn_mfma_f32_16x16x32_bf16
#define MFMA32 __builtin_amdgcn_mfma_f32_32x32x16_bf16

__device__ __forceinline__ u16 f2b(float f) {
  unsigned u = __builtin_bit_cast(unsigned, f);
  u = (u + 0x7fffu + ((u >> 16) & 1u)) >> 16;
  return (u16)u;
}

__device__ __forceinline__ void gload_lds16(const u16* g, u16* l) {
  __builtin_amdgcn_global_load_lds((const __attribute__((address_space(1))) void*)g,
                                   (__attribute__((address_space(3))) void*)l, 16, 0, 0);
}

// ---- fused prep: z<2 -> f32->bf16 convert of x/ctx; z=2 -> weight transpose ----
__global__ void prep(const float* __restrict__ x, const float* __restrict__ ctx,
                     u16* __restrict__ xb, u16* __restrict__ cb,
                     const float* __restrict__ w0, const float* __restrict__ w1,
                     const float* __restrict__ w2, const float* __restrict__ w3,
                     u16* __restrict__ o0, u16* __restrict__ o1,
                     u16* __restrict__ o2, u16* __restrict__ o3) {
  __shared__ float t[64][65];
  const int z = blockIdx.z;
  const int tid = threadIdx.x;
  if (z < 2) {
    int i = blockIdx.x * blockDim.x + tid;
    const float* in = z ? ctx : x;
    u16* out = z ? cb : xb;
    float4 v = reinterpret_cast<const float4*>(in)[i];
    reinterpret_cast<ushort4*>(out)[i] = make_ushort4(f2b(v.x), f2b(v.y), f2b(v.z), f2b(v.w));
    return;
  }
  const int id = blockIdx.x;
  if (id >= 1024) return;
  const int wsel = id >> 8;
  const float* src = wsel == 0 ? w0 : wsel == 1 ? w1 : wsel == 2 ? w2 : w3;
  u16* dst = wsel == 0 ? o0 : wsel == 1 ? o1 : wsel == 2 ? o2 : o3;
  const int r0 = ((id >> 4) & 15) * 64, c0 = (id & 15) * 64;
  #pragma unroll
  for (int it = 0; it < 4; ++it) {
    int row = it * 16 + (tid >> 4);
    int col = (tid & 15) * 4;
    float4 v = *reinterpret_cast<const float4*>(&src[(size_t)(r0 + row) * 1024 + c0 + col]);
    t[row][col] = v.x; t[row][col + 1] = v.y; t[row][col + 2] = v.z; t[row][col + 3] = v.w;
  }
  __syncthreads();
  #pragma unroll
  for (int it = 0; it < 2; ++it) {
    int c = it * 32 + (tid >> 3);
    int r8 = (tid & 7) * 8;
    u16 tmp[8];
    #pragma unroll
    for (int k = 0; k < 8; ++k) tmp[k] = f2b(t[r8 + k][c]);
    uint4 pk;
    pk.x = (unsigned)tmp[0] | ((unsigned)tmp[1] << 16);
    pk.y = (unsigned)tmp[2] | ((unsigned)tmp[3] << 16);
    pk.z = (unsigned)tmp[4] | ((unsigned)tmp[5] << 16);
    pk.w = (unsigned)tmp[6] | ((unsigned)tmp[7] << 16);
    *reinterpret_cast<uint4*>(&dst[(size_t)(c0 + c) * 1024 + r0 + r8]) = pk;
  }
}

// ---- shared GEMM mainloop, BK=64, FRAGMENT-ORDER LDS (conflict-free reads) ----
// Tile = 1024 chunks x 16B per operand. Chunk c=[ks:1][rb:1][idx:2][lane:6] holds
// A[row = rb*64 + idx*16 + (l&15)][k = ks*32 + (l>>4)*8 ..+8]  (B same on cols).
// Mainloop ds_read_b128 = wave-uniform base + lane*16B -> zero bank conflicts.
// The permutation lives in each thread's precomputed GLOBAL source offset; the
// LDS destination of global_load_lds stays linear. Schedule identical to R9.
__device__ __forceinline__ void gemm_core(const u16* __restrict__ A, const u16* __restrict__ Wt,
                                          f32x4 (&acc)[4][4], int brow, int bcol,
                                          u16* __restrict__ smem) {
  const int tid = threadIdx.x;
  const int lane = tid & 63;
  const int w = tid >> 6;
  const int wr = w >> 1, wc = w & 1;

  int aoff[4], boff[4];
  #pragma unroll
  for (int it = 0; it < 4; ++it) {
    const int c = it * 256 + tid;
    const int l = c & 63;
    const int row = ((c >> 8) & 1) * 64 + ((c >> 6) & 3) * 16 + (l & 15);
    const int kk = (c >> 9) * 32 + (l >> 4) * 8;
    aoff[it] = (brow + row) * 1024 + kk;
    boff[it] = (bcol + row) * 1024 + kk;
  }

  auto stage = [&](int buf, int kt) {
    #pragma unroll
    for (int it = 0; it < 4; ++it) {
      gload_lds16(&A[(size_t)(aoff[it] + kt * 64)],
                  &smem[buf * 8192 + (it * 256 + w * 64) * 8]);
      gload_lds16(&Wt[(size_t)(boff[it] + kt * 64)],
                  &smem[16384 + buf * 8192 + (it * 256 + w * 64) * 8]);
    }
  };

  stage(0, 0);
  __syncthreads();
  int cur = 0;
  for (int kt = 0; kt < 16; ++kt) {
    if (kt < 15) stage(cur ^ 1, kt + 1);
    const u16* As = &smem[cur * 8192];
    const u16* Bs = &smem[16384 + cur * 8192];
    #pragma unroll
    for (int ks = 0; ks < 2; ++ks) {
      bf16x8 a[4], b[4];
      #pragma unroll
      for (int mi = 0; mi < 4; ++mi)
        a[mi] = *reinterpret_cast<const bf16x8*>(&As[(ks * 512 + wr * 256 + mi * 64 + lane) * 8]);
      #pragma unroll
      for (int ni = 0; ni < 4; ++ni)
        b[ni] = *reinterpret_cast<const bf16x8*>(&Bs[(ks * 512 + wc * 256 + ni * 64 + lane) * 8]);
      #pragma unroll
      for (int mi = 0; mi < 4; ++mi)
        #pragma unroll
        for (int ni = 0; ni < 4; ++ni)
          acc[mi][ni] = MFMA16(a[mi], b[ni], acc[mi][ni], 0, 0, 0);
    }
    __syncthreads();
    cur ^= 1;
  }
}

// ---- fused Q/K/V projection ----
// z=0: Q row-major bf16, pre-scaled by SCALE*log2e.
// z=1: K in attn fragment order Kf[b,h][kt][512 chunks]x16B.
// z=2: V in attn fragment order Vf[b,h][kt][512 chunks]x16B.
__global__ __launch_bounds__(256, 2) void gemm_qkv(const u16* __restrict__ xb, const u16* __restrict__ cb,
                                                   const u16* __restrict__ Wqt, const u16* __restrict__ Wkt,
                                                   const u16* __restrict__ Wvt,
                                                   const float* __restrict__ bq, const float* __restrict__ bk,
                                                   const float* __restrict__ bv,
                                                   u16* __restrict__ Qb, u16* __restrict__ Kf,
                                                   u16* __restrict__ Vf) {
  __shared__ u16 smem[32768];
  const int z = blockIdx.z;
  const u16* A = z == 0 ? xb : cb;
  const u16* W = z == 0 ? Wqt : z == 1 ? Wkt : Wvt;
  const float* bias = z == 0 ? bq : z == 1 ? bk : bv;
  const int brow = blockIdx.x * 128, bcol = blockIdx.y * 128;
  f32x4 acc[4][4] = {};
  gemm_core(A, W, acc, brow, bcol, smem);

  const int lane = threadIdx.x & 63;
  const int w = threadIdx.x >> 6;
  const int wr = w >> 1, wc = w & 1;
  const int l16 = lane & 15, g = lane >> 4;
  const float CS = 0.125f * 1.44269504089f;
  u16* T = &smem[w * 5120];  // 64 rows x 80 cols (160B pitch: conflict-free b128 readback)

  if (z < 2) {
    #pragma unroll
    for (int ni = 0; ni < 4; ++ni) {
      const float bz = bias[bcol + wc * 64 + ni * 16 + l16];
      #pragma unroll
      for (int mi = 0; mi < 4; ++mi) {
        f32x4 v = acc[mi][ni];
        #pragma unroll
        for (int j = 0; j < 4; ++j) {
          float val = v[j] + bz;
          if (z == 0) val *= CS;
          T[(mi * 16 + g * 4 + j) * 80 + ni * 16 + l16] = f2b(val);
        }
      }
    }
    const int r0b = brow + wr * 64;
    const int colb = bcol + wc * 64;
    if (z == 0) {
      #pragma unroll
      for (int it = 0; it < 8; ++it) {
        const int rl = it * 8 + (lane >> 3);
        const int c8 = (lane & 7) * 8;
        bf16x8 val = *reinterpret_cast<const bf16x8*>(&T[rl * 80 + c8]);
        *reinterpret_cast<bf16x8*>(&Qb[(size_t)(r0b + rl) * 1024 + colb + c8]) = val;
      }
    } else {
      const int h = colb >> 6;
      const int bb = r0b >> 10;
      const int kt = (r0b & 1023) >> 6;
      u16* kb2 = &Kf[(((size_t)(bb * 16 + h)) * 16 + kt) * 4096];
      #pragma unroll
      for (int it = 0; it < 8; ++it) {
        const int rl = it * 8 + (lane >> 3);
        const int c8 = (lane & 7) * 8;
        bf16x8 val = *reinterpret_cast<const bf16x8*>(&T[rl * 80 + c8]);
        const int chunk = (c8 >> 4) * 128 + (rl >> 5) * 64 + ((c8 >> 3) & 1) * 32 + (rl & 31);
        *reinterpret_cast<bf16x8*>(&kb2[chunk * 8]) = val;
      }
    }
  } else {
    #pragma unroll
    for (int ni = 0; ni < 4; ++ni) {
      const float bz = bias[bcol + wc * 64 + ni * 16 + l16];
      #pragma unroll
      for (int mi = 0; mi < 4; ++mi) {
        f32x4 v = acc[mi][ni];
        #pragma unroll
        for (int j = 0; j < 4; ++j)
          T[(ni * 16 + l16) * 80 + mi * 16 + g * 4 + j] = f2b(v[j] + bz);
      }
    }
    const int h = (bcol + wc * 64) >> 6;
    const int m0 = brow + wr * 64;
    const int bb = m0 >> 10;
    const int kt = (m0 & 1023) >> 6;
    u16* vb = &Vf[(((size_t)(bb * 16 + h)) * 16 + kt) * 4096];
    #pragma unroll
    for (int it = 0; it < 8; ++it) {
      const int d = it * 8 + (lane >> 3);
      const int m8 = (lane & 7) * 8;
      bf16x8 val = *reinterpret_cast<const bf16x8*>(&T[d * 80 + m8]);
      const int chunk = (m8 >> 4) * 128 + (d >> 5) * 64 + ((m8 >> 3) & 1) * 32 + (d & 31);
      *reinterpret_cast<bf16x8*>(&vb[chunk * 8]) = val;
    }
  }
}

// ---- output projection: fp32 out ----
__global__ __launch_bounds__(256, 2) void gemm_o(const u16* __restrict__ A, const u16* __restrict__ Wt,
                                                 const float* __restrict__ bias, float* __restrict__ outp) {
  __shared__ u16 smem[32768];
  const int brow = blockIdx.x * 128, bcol = blockIdx.y * 128;
  f32x4 acc[4][4] = {};
  gemm_core(A, Wt, acc, brow, bcol, smem);
  const int lane = threadIdx.x & 63;
  const int w = threadIdx.x >> 6;
  const int wr = w >> 1, wc = w & 1;
  const int l16 = lane & 15, g = lane >> 4;
  #pragma unroll
  for (int ni = 0; ni < 4; ++ni) {
    const int col = bcol + wc * 64 + ni * 16 + l16;
    const float bz = bias[col];
    #pragma unroll
    for (int mi = 0; mi < 4; ++mi) {
      const int r0 = brow + wr * 64 + mi * 16 + g * 4;
      f32x4 v = acc[mi][ni];
      #pragma unroll
      for (int j = 0; j < 4; ++j) outp[(size_t)(r0 + j) * 1024 + col] = v[j] + bz;
    }
  }
}

// ---- flash attention: 256 q-rows/block (8 waves x 32), fragment-order K/V ----
__global__ __launch_bounds__(512, 4) void attn2(const u16* __restrict__ Q, const u16* __restrict__ Kf,
                                                const u16* __restrict__ Vf, u16* __restrict__ AO) {
  __shared__ u16 Ks[2][64 * 64];
  __shared__ u16 Vs[2][64 * 64];
  const int tid = threadIdx.x, lane = tid & 63, w = tid >> 6;  // w: 0..7
  const int l32 = lane & 31, u = lane >> 5;
  // XCD-bijective swizzle: 512 blocks, 8 XCDs -> XCD x owns 64 contiguous ids.
  const int id = blockIdx.x;
  const int v = (id & 7) * 64 + (id >> 3);
  const int qt = v & 3, h = (v >> 2) & 15, b = v >> 6;
  const int q0 = qt * 256 + w * 32;

  bf16x8 qf[4];
  {
    const u16* qp = &Q[(size_t)(b * 1024 + q0 + l32) * 1024 + h * 64 + u * 8];
    #pragma unroll
    for (int m = 0; m < 4; ++m) qf[m] = *reinterpret_cast<const bf16x8*>(qp + m * 16);
  }

  f32x16 o0 = {}, o1 = {};
  float lr = 0.f;

  const u16* Kbh = Kf + (size_t)(b * 16 + h) * 65536;
  const u16* Vbh = Vf + (size_t)(b * 16 + h) * 65536;

  auto stage = [&](int buf, int kt) {
    const int c = tid * 8;
    gload_lds16(&Kbh[kt * 4096 + c], &Ks[buf][(w * 64) * 8]);
    gload_lds16(&Vbh[kt * 4096 + c], &Vs[buf][(w * 64) * 8]);
  };

  stage(0, 0);
  __syncthreads();
  int cur = 0;

  for (int kt = 0; kt < 16; ++kt) {
    if (kt < 15) stage(cur ^ 1, kt + 1);

    f32x16 s0 = {}, s1 = {};
    __builtin_amdgcn_s_setprio(1);
    #pragma unroll
    for (int m = 0; m < 4; ++m) {
      bf16x8 k0 = *reinterpret_cast<const bf16x8*>(&Ks[cur][m * 1024 + lane * 8]);
      bf16x8 k1 = *reinterpret_cast<const bf16x8*>(&Ks[cur][m * 1024 + 512 + lane * 8]);
      s0 = MFMA32(k0, qf[m], s0, 0, 0, 0);
      s1 = MFMA32(k1, qf[m], s1, 0, 0, 0);
    }
    __builtin_amdgcn_s_setprio(0);

    unsigned W0[8], W1[8];
    #pragma unroll
    for (int j = 0; j < 8; ++j) {
      const int r = 4 * (j >> 1) + 2 * (j & 1);
      float pa0 = __builtin_amdgcn_exp2f(s0[r]);
      float pb0 = __builtin_amdgcn_exp2f(s0[r + 1]);
      float pa1 = __builtin_amdgcn_exp2f(s1[r]);
      float pb1 = __builtin_amdgcn_exp2f(s1[r + 1]);
      lr += (pa0 + pb0) + (pa1 + pb1);
      asm("v_cvt_pk_bf16_f32 %0, %1, %2" : "=v"(W0[j]) : "v"(pa0), "v"(pb0));
      asm("v_cvt_pk_bf16_f32 %0, %1, %2" : "=v"(W1[j]) : "v"(pa1), "v"(pb1));
    }

    unsigned paw[4][4];
    #pragma unroll
    for (int ks = 0; ks < 4; ++ks) {
      const int ksl = ks & 1;
      #pragma unroll
      for (int p = 0; p < 2; ++p) {
        unsigned x = (ks < 2) ? W0[4 * ksl + p] : W1[4 * ksl + p];
        unsigned y = (ks < 2) ? W0[4 * ksl + 2 + p] : W1[4 * ksl + 2 + p];
        asm("v_permlane32_swap_b32 %0, %1" : "+v"(x), "+v"(y));
        paw[ks][p] = x;
        paw[ks][2 + p] = y;
      }
    }

    __builtin_amdgcn_s_setprio(1);
    #pragma unroll
    for (int ks = 0; ks < 4; ++ks) {
      bf16x8 pa = __builtin_bit_cast(bf16x8, u32x4{paw[ks][0], paw[ks][1], paw[ks][2], paw[ks][3]});
      bf16x8 v0 = *reinterpret_cast<const bf16x8*>(&Vs[cur][ks * 1024 + lane * 8]);
      bf16x8 v1 = *reinterpret_cast<const bf16x8*>(&Vs[cur][ks * 1024 + 512 + lane * 8]);
      o0 = MFMA32(pa, v0, o0, 0, 0, 0);
      o1 = MFMA32(pa, v1, o1, 0, 0, 0);
    }
    __builtin_amdgcn_s_setprio(0);

    __syncthreads();
    cur ^= 1;
  }

  float sum = lr + __shfl_xor(lr, 32);
  float rinv = 1.0f / sum;
  u16* aop = &AO[(size_t)(b * 1024 + q0) * 1024 + h * 64 + l32];
  #pragma unroll
  for (int r = 0; r < 16; ++r) {
    const int ql = (r & 3) + 8 * (r >> 2) + 4 * u;
    int ri_i = __builtin_amdgcn_ds_bpermute((ql + (u << 5)) << 2, __builtin_bit_cast(int, rinv));
    float ri = __builtin_bit_cast(float, ri_i);
    aop[(size_t)ql * 1024] = f2b(o0[r] * ri);
    aop[(size_t)ql * 1024 + 32] = f2b(o1[r] * ri);
  }
}

extern "C" void kernel_launch(void* const* d_in, const int* in_sizes, int n_in,
                              void* d_out, int out_size, void* d_ws, size_t ws_size,
                              hipStream_t stream) {
  const float* x   = (const float*)d_in[0];
  const float* ctx = (const float*)d_in[1];
  const float* Wq  = (const float*)d_in[2];
  const float* bq  = (const float*)d_in[3];
  const float* Wk  = (const float*)d_in[4];
  const float* bk  = (const float*)d_in[5];
  const float* Wv  = (const float*)d_in[6];
  const float* bv  = (const float*)d_in[7];
  const float* Wo  = (const float*)d_in[8];
  const float* bo  = (const float*)d_in[9];
  float* out = (float*)d_out;
  char* ws = (char*)d_ws;

  u16* xb  = (u16*)(ws + (size_t)0);          // 16MB (also reused as AO)
  u16* cb  = (u16*)(ws + ((size_t)16 << 20));
  u16* Qb  = (u16*)(ws + ((size_t)32 << 20));
  u16* Kf  = (u16*)(ws + ((size_t)48 << 20));
  u16* Vf  = (u16*)(ws + ((size_t)64 << 20));
  u16* Wqt = (u16*)(ws + ((size_t)80 << 20));
  u16* Wkt = (u16*)(ws + ((size_t)82 << 20));
  u16* Wvt = (u16*)(ws + ((size_t)84 << 20));
  u16* Wot = (u16*)(ws + ((size_t)86 << 20));

  prep<<<dim3(8192, 1, 3), 256, 0, stream>>>(x, ctx, xb, cb, Wq, Wk, Wv, Wo, Wqt, Wkt, Wvt, Wot);
  gemm_qkv<<<dim3(64, 8, 3), 256, 0, stream>>>(xb, cb, Wqt, Wkt, Wvt, bq, bk, bv, Qb, Kf, Vf);
  attn2<<<dim3(512), 512, 0, stream>>>(Qb, Kf, Vf, xb /*AO*/);
  gemm_o<<<dim3(64, 8), 256, 0, stream>>>(xb, Wot, bo, out);
}

// Round 13
// 155.185 us; speedup vs baseline: 1.2734x; 1.2734x over previous
//
#include <hip/hip_runtime.h>

typedef unsigned short u16;
typedef __attribute__((ext_vector_type(8))) short bf16x8;
typedef __attribute__((ext_vector_type(4))) float f32x4;
typedef __attribute__((ext_vector_type(16))) float f32x16;
typedef __attribute__((ext_vector_type(4))) unsigned u32x4;

#define MFMA16 __builtin_amdgcn_mfma_f32_16x16x32_bf16
#define MFMA32 __builtin_amdgcn_mfma_f32_32x32x16_bf16

__device__ __forceinline__ u16 f2b(float f) {
  unsigned u = __builtin_bit_cast(unsigned, f);
  u = (u + 0x7fffu + ((u >> 16) & 1u)) >> 16;
  return (u16)u;
}

__device__ __forceinline__ void gload_lds16(const u16* g, u16* l) {
  __builtin_amdgcn_global_load_lds((const __attribute__((address_space(1))) void*)g,
                                   (__attribute__((address_space(3))) void*)l, 16, 0, 0);
}

// ---- fused prep: z<2 -> f32->bf16 convert of x/ctx; z=2 -> weight transpose ----
__global__ void prep(const float* __restrict__ x, const float* __restrict__ ctx,
                     u16* __restrict__ xb, u16* __restrict__ cb,
                     const float* __restrict__ w0, const float* __restrict__ w1,
                     const float* __restrict__ w2, const float* __restrict__ w3,
                     u16* __restrict__ o0, u16* __restrict__ o1,
                     u16* __restrict__ o2, u16* __restrict__ o3) {
  __shared__ float t[64][65];
  const int z = blockIdx.z;
  const int tid = threadIdx.x;
  if (z < 2) {
    int i = blockIdx.x * blockDim.x + tid;
    const float* in = z ? ctx : x;
    u16* out = z ? cb : xb;
    float4 v = reinterpret_cast<const float4*>(in)[i];
    reinterpret_cast<ushort4*>(out)[i] = make_ushort4(f2b(v.x), f2b(v.y), f2b(v.z), f2b(v.w));
    return;
  }
  const int id = blockIdx.x;
  if (id >= 1024) return;
  const int wsel = id >> 8;
  const float* src = wsel == 0 ? w0 : wsel == 1 ? w1 : wsel == 2 ? w2 : w3;
  u16* dst = wsel == 0 ? o0 : wsel == 1 ? o1 : wsel == 2 ? o2 : o3;
  const int r0 = ((id >> 4) & 15) * 64, c0 = (id & 15) * 64;
  #pragma unroll
  for (int it = 0; it < 4; ++it) {
    int row = it * 16 + (tid >> 4);
    int col = (tid & 15) * 4;
    float4 v = *reinterpret_cast<const float4*>(&src[(size_t)(r0 + row) * 1024 + c0 + col]);
    t[row][col] = v.x; t[row][col + 1] = v.y; t[row][col + 2] = v.z; t[row][col + 3] = v.w;
  }
  __syncthreads();
  #pragma unroll
  for (int it = 0; it < 2; ++it) {
    int c = it * 32 + (tid >> 3);
    int r8 = (tid & 7) * 8;
    u16 tmp[8];
    #pragma unroll
    for (int k = 0; k < 8; ++k) tmp[k] = f2b(t[r8 + k][c]);
    uint4 pk;
    pk.x = (unsigned)tmp[0] | ((unsigned)tmp[1] << 16);
    pk.y = (unsigned)tmp[2] | ((unsigned)tmp[3] << 16);
    pk.z = (unsigned)tmp[4] | ((unsigned)tmp[5] << 16);
    pk.w = (unsigned)tmp[6] | ((unsigned)tmp[7] << 16);
    *reinterpret_cast<uint4*>(&dst[(size_t)(c0 + c) * 1024 + r0 + r8]) = pk;
  }
}

// ---- shared GEMM mainloop, BK=64 (R9 proven form: split-k LDS [ks][128][32]) ----
__device__ __forceinline__ void gemm_core(const u16* __restrict__ A, const u16* __restrict__ Wt,
                                          f32x4 (&acc)[4][4], int brow, int bcol,
                                          u16* __restrict__ smem) {
  const int tid = threadIdx.x;
  const int lane = tid & 63;
  const int w = tid >> 6;
  const int wr = w >> 1, wc = w & 1;
  const int l16 = lane & 15, g = lane >> 4;

  auto stage = [&](int buf, int kt) {
    #pragma unroll
    for (int it = 0; it < 4; ++it) {
      int c = it * 256 + tid;
      int row = (c >> 2) & 127;
      int ks = c >> 9;
      int k8 = c & 3;
      const size_t gofs = (size_t)kt * 64 + ks * 32 + k8 * 8;
      gload_lds16(&A[(size_t)(brow + row) * 1024 + gofs],
                  &smem[buf * 8192 + (it * 256 + w * 64) * 8]);
      gload_lds16(&Wt[(size_t)(bcol + row) * 1024 + gofs],
                  &smem[16384 + buf * 8192 + (it * 256 + w * 64) * 8]);
    }
  };

  stage(0, 0);
  __syncthreads();
  int cur = 0;
  for (int kt = 0; kt < 16; ++kt) {
    if (kt < 15) stage(cur ^ 1, kt + 1);
    const u16* As = &smem[cur * 8192];
    const u16* Bs = &smem[16384 + cur * 8192];
    #pragma unroll
    for (int ks = 0; ks < 2; ++ks) {
      bf16x8 a[4], b[4];
      const int kb = ks * 4096 + g * 8;
      #pragma unroll
      for (int mi = 0; mi < 4; ++mi)
        a[mi] = *reinterpret_cast<const bf16x8*>(&As[kb + (wr * 64 + mi * 16 + l16) * 32]);
      #pragma unroll
      for (int ni = 0; ni < 4; ++ni)
        b[ni] = *reinterpret_cast<const bf16x8*>(&Bs[kb + (wc * 64 + ni * 16 + l16) * 32]);
      #pragma unroll
      for (int mi = 0; mi < 4; ++mi)
        #pragma unroll
        for (int ni = 0; ni < 4; ++ni)
          acc[mi][ni] = MFMA16(a[mi], b[ni], acc[mi][ni], 0, 0, 0);
    }
    __syncthreads();
    cur ^= 1;
  }
}

// ---- fused Q/K/V projection (R9 proven form) ----
// z=0: Q row-major bf16, pre-scaled by SCALE*log2e.
// z=1: K in attn fragment order Kf[b,h][kt][512 chunks]x16B.
// z=2: V in attn fragment order Vf[b,h][kt][512 chunks]x16B.
__global__ __launch_bounds__(256, 2) void gemm_qkv(const u16* __restrict__ xb, const u16* __restrict__ cb,
                                                   const u16* __restrict__ Wqt, const u16* __restrict__ Wkt,
                                                   const u16* __restrict__ Wvt,
                                                   const float* __restrict__ bq, const float* __restrict__ bk,
                                                   const float* __restrict__ bv,
                                                   u16* __restrict__ Qb, u16* __restrict__ Kf,
                                                   u16* __restrict__ Vf) {
  __shared__ u16 smem[32768];
  const int z = blockIdx.z;
  const u16* A = z == 0 ? xb : cb;
  const u16* W = z == 0 ? Wqt : z == 1 ? Wkt : Wvt;
  const float* bias = z == 0 ? bq : z == 1 ? bk : bv;
  const int brow = blockIdx.x * 128, bcol = blockIdx.y * 128;
  f32x4 acc[4][4] = {};
  gemm_core(A, W, acc, brow, bcol, smem);

  const int lane = threadIdx.x & 63;
  const int w = threadIdx.x >> 6;
  const int wr = w >> 1, wc = w & 1;
  const int l16 = lane & 15, g = lane >> 4;
  const float CS = 0.125f * 1.44269504089f;
  u16* T = &smem[w * 5120];  // 64 rows x 80 cols (160B pitch: conflict-free b128 readback)

  if (z < 2) {
    #pragma unroll
    for (int ni = 0; ni < 4; ++ni) {
      const float bz = bias[bcol + wc * 64 + ni * 16 + l16];
      #pragma unroll
      for (int mi = 0; mi < 4; ++mi) {
        f32x4 v = acc[mi][ni];
        #pragma unroll
        for (int j = 0; j < 4; ++j) {
          float val = v[j] + bz;
          if (z == 0) val *= CS;
          T[(mi * 16 + g * 4 + j) * 80 + ni * 16 + l16] = f2b(val);
        }
      }
    }
    const int r0b = brow + wr * 64;
    const int colb = bcol + wc * 64;
    if (z == 0) {
      #pragma unroll
      for (int it = 0; it < 8; ++it) {
        const int rl = it * 8 + (lane >> 3);
        const int c8 = (lane & 7) * 8;
        bf16x8 val = *reinterpret_cast<const bf16x8*>(&T[rl * 80 + c8]);
        *reinterpret_cast<bf16x8*>(&Qb[(size_t)(r0b + rl) * 1024 + colb + c8]) = val;
      }
    } else {
      const int h = colb >> 6;
      const int bb = r0b >> 10;
      const int kt = (r0b & 1023) >> 6;
      u16* kb2 = &Kf[(((size_t)(bb * 16 + h)) * 16 + kt) * 4096];
      #pragma unroll
      for (int it = 0; it < 8; ++it) {
        const int rl = it * 8 + (lane >> 3);
        const int c8 = (lane & 7) * 8;
        bf16x8 val = *reinterpret_cast<const bf16x8*>(&T[rl * 80 + c8]);
        const int chunk = (c8 >> 4) * 128 + (rl >> 5) * 64 + ((c8 >> 3) & 1) * 32 + (rl & 31);
        *reinterpret_cast<bf16x8*>(&kb2[chunk * 8]) = val;
      }
    }
  } else {
    #pragma unroll
    for (int ni = 0; ni < 4; ++ni) {
      const float bz = bias[bcol + wc * 64 + ni * 16 + l16];
      #pragma unroll
      for (int mi = 0; mi < 4; ++mi) {
        f32x4 v = acc[mi][ni];
        #pragma unroll
        for (int j = 0; j < 4; ++j)
          T[(ni * 16 + l16) * 80 + mi * 16 + g * 4 + j] = f2b(v[j] + bz);
      }
    }
    const int h = (bcol + wc * 64) >> 6;
    const int m0 = brow + wr * 64;
    const int bb = m0 >> 10;
    const int kt = (m0 & 1023) >> 6;
    u16* vb = &Vf[(((size_t)(bb * 16 + h)) * 16 + kt) * 4096];
    #pragma unroll
    for (int it = 0; it < 8; ++it) {
      const int d = it * 8 + (lane >> 3);
      const int m8 = (lane & 7) * 8;
      bf16x8 val = *reinterpret_cast<const bf16x8*>(&T[d * 80 + m8]);
      const int chunk = (m8 >> 4) * 128 + (d >> 5) * 64 + ((m8 >> 3) & 1) * 32 + (d & 31);
      *reinterpret_cast<bf16x8*>(&vb[chunk * 8]) = val;
    }
  }
}

// ---- output projection: fp32 out ----
__global__ __launch_bounds__(256, 2) void gemm_o(const u16* __restrict__ A, const u16* __restrict__ Wt,
                                                 const float* __restrict__ bias, float* __restrict__ outp) {
  __shared__ u16 smem[32768];
  const int brow = blockIdx.x * 128, bcol = blockIdx.y * 128;
  f32x4 acc[4][4] = {};
  gemm_core(A, Wt, acc, brow, bcol, smem);
  const int lane = threadIdx.x & 63;
  const int w = threadIdx.x >> 6;
  const int wr = w >> 1, wc = w & 1;
  const int l16 = lane & 15, g = lane >> 4;
  #pragma unroll
  for (int ni = 0; ni < 4; ++ni) {
    const int col = bcol + wc * 64 + ni * 16 + l16;
    const float bz = bias[col];
    #pragma unroll
    for (int mi = 0; mi < 4; ++mi) {
      const int r0 = brow + wr * 64 + mi * 16 + g * 4;
      f32x4 v = acc[mi][ni];
      #pragma unroll
      for (int j = 0; j < 4; ++j) outp[(size_t)(r0 + j) * 1024 + col] = v[j] + bz;
    }
  }
}

// ---- flash attention v3: NO K/V staging (direct L2-resident global reads,
// zero barriers in the loop), 256 q-rows/block, coalesced epilogue via LDS ----
__global__ __launch_bounds__(512, 4) void attn2(const u16* __restrict__ Q, const u16* __restrict__ Kf,
                                                const u16* __restrict__ Vf, u16* __restrict__ AO) {
  __shared__ u16 Ts[16384];  // per-wave 32x64 epilogue tile (w*2048)
  const int tid = threadIdx.x, lane = tid & 63, w = tid >> 6;  // w: 0..7
  const int l32 = lane & 31, u = lane >> 5;
  // XCD-bijective swizzle: 512 blocks, 8 XCDs -> XCD x owns 64 contiguous ids
  // = 16 contiguous (b,h) pairs; K/V working set 16 x 256KB = 4MB = one L2.
  const int id = blockIdx.x;
  const int v = (id & 7) * 64 + (id >> 3);
  const int qt = v & 3, h = (v >> 2) & 15, b = v >> 6;
  const int q0 = qt * 256 + w * 32;

  bf16x8 qf[4];
  {
    const u16* qp = &Q[(size_t)(b * 1024 + q0 + l32) * 1024 + h * 64 + u * 8];
    #pragma unroll
    for (int m = 0; m < 4; ++m) qf[m] = *reinterpret_cast<const bf16x8*>(qp + m * 16);
  }

  f32x16 o0 = {}, o1 = {};
  float lr = 0.f;

  const u16* Kbh = Kf + (size_t)(b * 16 + h) * 65536;  // frag-order: identity chunk stream
  const u16* Vbh = Vf + (size_t)(b * 16 + h) * 65536;

  for (int kt = 0; kt < 16; ++kt) {
    const u16* Kt = Kbh + kt * 4096;
    const u16* Vt = Vbh + kt * 4096;

    f32x16 s0 = {}, s1 = {};
    #pragma unroll
    for (int m = 0; m < 4; ++m) {
      bf16x8 k0 = *reinterpret_cast<const bf16x8*>(&Kt[m * 1024 + lane * 8]);
      bf16x8 k1 = *reinterpret_cast<const bf16x8*>(&Kt[m * 1024 + 512 + lane * 8]);
      __builtin_amdgcn_s_setprio(1);
      s0 = MFMA32(k0, qf[m], s0, 0, 0, 0);
      s1 = MFMA32(k1, qf[m], s1, 0, 0, 0);
      __builtin_amdgcn_s_setprio(0);
    }

    unsigned W0[8], W1[8];
    #pragma unroll
    for (int j = 0; j < 8; ++j) {
      const int r = 4 * (j >> 1) + 2 * (j & 1);
      float pa0 = __builtin_amdgcn_exp2f(s0[r]);
      float pb0 = __builtin_amdgcn_exp2f(s0[r + 1]);
      float pa1 = __builtin_amdgcn_exp2f(s1[r]);
      float pb1 = __builtin_amdgcn_exp2f(s1[r + 1]);
      lr += (pa0 + pb0) + (pa1 + pb1);
      asm("v_cvt_pk_bf16_f32 %0, %1, %2" : "=v"(W0[j]) : "v"(pa0), "v"(pb0));
      asm("v_cvt_pk_bf16_f32 %0, %1, %2" : "=v"(W1[j]) : "v"(pa1), "v"(pb1));
    }

    unsigned paw[4][4];
    #pragma unroll
    for (int ks = 0; ks < 4; ++ks) {
      const int ksl = ks & 1;
      #pragma unroll
      for (int p = 0; p < 2; ++p) {
        unsigned x = (ks < 2) ? W0[4 * ksl + p] : W1[4 * ksl + p];
        unsigned y = (ks < 2) ? W0[4 * ksl + 2 + p] : W1[4 * ksl + 2 + p];
        asm("v_permlane32_swap_b32 %0, %1" : "+v"(x), "+v"(y));
        paw[ks][p] = x;
        paw[ks][2 + p] = y;
      }
    }

    #pragma unroll
    for (int ks = 0; ks < 4; ++ks) {
      bf16x8 pa = __builtin_bit_cast(bf16x8, u32x4{paw[ks][0], paw[ks][1], paw[ks][2], paw[ks][3]});
      bf16x8 v0 = *reinterpret_cast<const bf16x8*>(&Vt[ks * 1024 + lane * 8]);
      bf16x8 v1 = *reinterpret_cast<const bf16x8*>(&Vt[ks * 1024 + 512 + lane * 8]);
      __builtin_amdgcn_s_setprio(1);
      o0 = MFMA32(pa, v0, o0, 0, 0, 0);
      o1 = MFMA32(pa, v1, o1, 0, 0, 0);
      __builtin_amdgcn_s_setprio(0);
    }
  }

  // ---- epilogue: per-wave XOR-swizzled LDS retile -> coalesced 16B stores ----
  float sum = lr + __shfl_xor(lr, 32);
  float rinv = 1.0f / sum;
  u16* T = &Ts[w * 2048];  // 32 rows x 64 cols, col index XOR-swizzled by row
  #pragma unroll
  for (int r = 0; r < 16; ++r) {
    const int ql = (r & 3) + 8 * (r >> 2) + 4 * u;
    int ri_i = __builtin_amdgcn_ds_bpermute((ql + (u << 5)) << 2, __builtin_bit_cast(int, rinv));
    float ri = __builtin_bit_cast(float, ri_i);
    const int sw = (ql & 7) << 3;
    T[ql * 64 + (l32 ^ sw)] = f2b(o0[r] * ri);
    T[ql * 64 + ((32 + l32) ^ sw)] = f2b(o1[r] * ri);
  }
  // wave-private region: compiler inserts lgkmcnt between ds ops; no barrier needed
  u16* aop = &AO[(size_t)(b * 1024 + q0) * 1024 + h * 64];
  #pragma unroll
  for (int it = 0; it < 4; ++it) {
    const int rl = it * 8 + (lane >> 3);
    const int c8 = (lane & 7) * 8;
    bf16x8 val = *reinterpret_cast<const bf16x8*>(&T[rl * 64 + (c8 ^ ((rl & 7) << 3))]);
    *reinterpret_cast<bf16x8*>(&aop[(size_t)rl * 1024 + c8]) = val;
  }
}

extern "C" void kernel_launch(void* const* d_in, const int* in_sizes, int n_in,
                              void* d_out, int out_size, void* d_ws, size_t ws_size,
                              hipStream_t stream) {
  const float* x   = (const float*)d_in[0];
  const float* ctx = (const float*)d_in[1];
  const float* Wq  = (const float*)d_in[2];
  const float* bq  = (const float*)d_in[3];
  const float* Wk  = (const float*)d_in[4];
  const float* bk  = (const float*)d_in[5];
  const float* Wv  = (const float*)d_in[6];
  const float* bv  = (const float*)d_in[7];
  const float* Wo  = (const float*)d_in[8];
  const float* bo  = (const float*)d_in[9];
  float* out = (float*)d_out;
  char* ws = (char*)d_ws;

  u16* xb  = (u16*)(ws + (size_t)0);          // 16MB (also reused as AO)
  u16* cb  = (u16*)(ws + ((size_t)16 << 20));
  u16* Qb  = (u16*)(ws + ((size_t)32 << 20));
  u16* Kf  = (u16*)(ws + ((size_t)48 << 20));
  u16* Vf  = (u16*)(ws + ((size_t)64 << 20));
  u16* Wqt = (u16*)(ws + ((size_t)80 << 20));
  u16* Wkt = (u16*)(ws + ((size_t)82 << 20));
  u16* Wvt = (u16*)(ws + ((size_t)84 << 20));
  u16* Wot = (u16*)(ws + ((size_t)86 << 20));

  prep<<<dim3(8192, 1, 3), 256, 0, stream>>>(x, ctx, xb, cb, Wq, Wk, Wv, Wo, Wqt, Wkt, Wvt, Wot);
  gemm_qkv<<<dim3(64, 8, 3), 256, 0, stream>>>(xb, cb, Wqt, Wkt, Wvt, bq, bk, bv, Qb, Kf, Vf);
  attn2<<<dim3(512), 512, 0, stream>>>(Qb, Kf, Vf, xb /*AO*/);
  gemm_o<<<dim3(64, 8), 256, 0, stream>>>(xb, Wot, bo, out);
}

// Round 14
// 148.206 us; speedup vs baseline: 1.3333x; 1.0471x over previous
//
#include <hip/hip_runtime.h>

typedef unsigned short u16;
typedef __attribute__((ext_vector_type(8))) short bf16x8;
typedef __attribute__((ext_vector_type(4))) float f32x4;
typedef __attribute__((ext_vector_type(16))) float f32x16;
typedef __attribute__((ext_vector_type(4))) unsigned u32x4;

#define MFMA16 __builtin_amdgcn_mfma_f32_16x16x32_bf16
#define MFMA32 __builtin_amdgcn_mfma_f32_32x32x16_bf16

__device__ __forceinline__ u16 f2b(float f) {
  unsigned u = __builtin_bit_cast(unsigned, f);
  u = (u + 0x7fffu + ((u >> 16) & 1u)) >> 16;
  return (u16)u;
}

__device__ __forceinline__ void gload_lds16(const u16* g, u16* l) {
  __builtin_amdgcn_global_load_lds((const __attribute__((address_space(1))) void*)g,
                                   (__attribute__((address_space(3))) void*)l, 16, 0, 0);
}

// ---- fused prep: z<2 -> f32->bf16 convert of x/ctx; z=2 -> weight transpose ----
__global__ void prep(const float* __restrict__ x, const float* __restrict__ ctx,
                     u16* __restrict__ xb, u16* __restrict__ cb,
                     const float* __restrict__ w0, const float* __restrict__ w1,
                     const float* __restrict__ w2, const float* __restrict__ w3,
                     u16* __restrict__ o0, u16* __restrict__ o1,
                     u16* __restrict__ o2, u16* __restrict__ o3) {
  __shared__ float t[64][65];
  const int z = blockIdx.z;
  const int tid = threadIdx.x;
  if (z < 2) {
    int i = blockIdx.x * blockDim.x + tid;
    const float* in = z ? ctx : x;
    u16* out = z ? cb : xb;
    float4 v = reinterpret_cast<const float4*>(in)[i];
    reinterpret_cast<ushort4*>(out)[i] = make_ushort4(f2b(v.x), f2b(v.y), f2b(v.z), f2b(v.w));
    return;
  }
  const int id = blockIdx.x;
  if (id >= 1024) return;
  const int wsel = id >> 8;
  const float* src = wsel == 0 ? w0 : wsel == 1 ? w1 : wsel == 2 ? w2 : w3;
  u16* dst = wsel == 0 ? o0 : wsel == 1 ? o1 : wsel == 2 ? o2 : o3;
  const int r0 = ((id >> 4) & 15) * 64, c0 = (id & 15) * 64;
  #pragma unroll
  for (int it = 0; it < 4; ++it) {
    int row = it * 16 + (tid >> 4);
    int col = (tid & 15) * 4;
    float4 v = *reinterpret_cast<const float4*>(&src[(size_t)(r0 + row) * 1024 + c0 + col]);
    t[row][col] = v.x; t[row][col + 1] = v.y; t[row][col + 2] = v.z; t[row][col + 3] = v.w;
  }
  __syncthreads();
  #pragma unroll
  for (int it = 0; it < 2; ++it) {
    int c = it * 32 + (tid >> 3);
    int r8 = (tid & 7) * 8;
    u16 tmp[8];
    #pragma unroll
    for (int k = 0; k < 8; ++k) tmp[k] = f2b(t[r8 + k][c]);
    uint4 pk;
    pk.x = (unsigned)tmp[0] | ((unsigned)tmp[1] << 16);
    pk.y = (unsigned)tmp[2] | ((unsigned)tmp[3] << 16);
    pk.z = (unsigned)tmp[4] | ((unsigned)tmp[5] << 16);
    pk.w = (unsigned)tmp[6] | ((unsigned)tmp[7] << 16);
    *reinterpret_cast<uint4*>(&dst[(size_t)(c0 + c) * 1024 + r0 + r8]) = pk;
  }
}

// ---- shared GEMM mainloop, BK=64 (R9 proven form: split-k LDS [ks][128][32]) ----
__device__ __forceinline__ void gemm_core(const u16* __restrict__ A, const u16* __restrict__ Wt,
                                          f32x4 (&acc)[4][4], int brow, int bcol,
                                          u16* __restrict__ smem) {
  const int tid = threadIdx.x;
  const int lane = tid & 63;
  const int w = tid >> 6;
  const int wr = w >> 1, wc = w & 1;
  const int l16 = lane & 15, g = lane >> 4;

  auto stage = [&](int buf, int kt) {
    #pragma unroll
    for (int it = 0; it < 4; ++it) {
      int c = it * 256 + tid;
      int row = (c >> 2) & 127;
      int ks = c >> 9;
      int k8 = c & 3;
      const size_t gofs = (size_t)kt * 64 + ks * 32 + k8 * 8;
      gload_lds16(&A[(size_t)(brow + row) * 1024 + gofs],
                  &smem[buf * 8192 + (it * 256 + w * 64) * 8]);
      gload_lds16(&Wt[(size_t)(bcol + row) * 1024 + gofs],
                  &smem[16384 + buf * 8192 + (it * 256 + w * 64) * 8]);
    }
  };

  stage(0, 0);
  __syncthreads();
  int cur = 0;
  for (int kt = 0; kt < 16; ++kt) {
    if (kt < 15) stage(cur ^ 1, kt + 1);
    const u16* As = &smem[cur * 8192];
    const u16* Bs = &smem[16384 + cur * 8192];
    #pragma unroll
    for (int ks = 0; ks < 2; ++ks) {
      bf16x8 a[4], b[4];
      const int kb = ks * 4096 + g * 8;
      #pragma unroll
      for (int mi = 0; mi < 4; ++mi)
        a[mi] = *reinterpret_cast<const bf16x8*>(&As[kb + (wr * 64 + mi * 16 + l16) * 32]);
      #pragma unroll
      for (int ni = 0; ni < 4; ++ni)
        b[ni] = *reinterpret_cast<const bf16x8*>(&Bs[kb + (wc * 64 + ni * 16 + l16) * 32]);
      #pragma unroll
      for (int mi = 0; mi < 4; ++mi)
        #pragma unroll
        for (int ni = 0; ni < 4; ++ni)
          acc[mi][ni] = MFMA16(a[mi], b[ni], acc[mi][ni], 0, 0, 0);
    }
    __syncthreads();
    cur ^= 1;
  }
}

// ---- fused Q/K/V projection (R9 proven form) ----
// z=0: Q row-major bf16, pre-scaled by SCALE*log2e.
// z=1: K in attn fragment order Kf[b,h][kt][512 chunks]x16B.
// z=2: V in attn fragment order Vf[b,h][kt][512 chunks]x16B.
__global__ __launch_bounds__(256, 2) void gemm_qkv(const u16* __restrict__ xb, const u16* __restrict__ cb,
                                                   const u16* __restrict__ Wqt, const u16* __restrict__ Wkt,
                                                   const u16* __restrict__ Wvt,
                                                   const float* __restrict__ bq, const float* __restrict__ bk,
                                                   const float* __restrict__ bv,
                                                   u16* __restrict__ Qb, u16* __restrict__ Kf,
                                                   u16* __restrict__ Vf) {
  __shared__ u16 smem[32768];
  const int z = blockIdx.z;
  const u16* A = z == 0 ? xb : cb;
  const u16* W = z == 0 ? Wqt : z == 1 ? Wkt : Wvt;
  const float* bias = z == 0 ? bq : z == 1 ? bk : bv;
  const int brow = blockIdx.x * 128, bcol = blockIdx.y * 128;
  f32x4 acc[4][4] = {};
  gemm_core(A, W, acc, brow, bcol, smem);

  const int lane = threadIdx.x & 63;
  const int w = threadIdx.x >> 6;
  const int wr = w >> 1, wc = w & 1;
  const int l16 = lane & 15, g = lane >> 4;
  const float CS = 0.125f * 1.44269504089f;
  u16* T = &smem[w * 5120];  // 64 rows x 80 cols (160B pitch: conflict-free b128 readback)

  if (z < 2) {
    #pragma unroll
    for (int ni = 0; ni < 4; ++ni) {
      const float bz = bias[bcol + wc * 64 + ni * 16 + l16];
      #pragma unroll
      for (int mi = 0; mi < 4; ++mi) {
        f32x4 v = acc[mi][ni];
        #pragma unroll
        for (int j = 0; j < 4; ++j) {
          float val = v[j] + bz;
          if (z == 0) val *= CS;
          T[(mi * 16 + g * 4 + j) * 80 + ni * 16 + l16] = f2b(val);
        }
      }
    }
    const int r0b = brow + wr * 64;
    const int colb = bcol + wc * 64;
    if (z == 0) {
      #pragma unroll
      for (int it = 0; it < 8; ++it) {
        const int rl = it * 8 + (lane >> 3);
        const int c8 = (lane & 7) * 8;
        bf16x8 val = *reinterpret_cast<const bf16x8*>(&T[rl * 80 + c8]);
        *reinterpret_cast<bf16x8*>(&Qb[(size_t)(r0b + rl) * 1024 + colb + c8]) = val;
      }
    } else {
      const int h = colb >> 6;
      const int bb = r0b >> 10;
      const int kt = (r0b & 1023) >> 6;
      u16* kb2 = &Kf[(((size_t)(bb * 16 + h)) * 16 + kt) * 4096];
      #pragma unroll
      for (int it = 0; it < 8; ++it) {
        const int rl = it * 8 + (lane >> 3);
        const int c8 = (lane & 7) * 8;
        bf16x8 val = *reinterpret_cast<const bf16x8*>(&T[rl * 80 + c8]);
        const int chunk = (c8 >> 4) * 128 + (rl >> 5) * 64 + ((c8 >> 3) & 1) * 32 + (rl & 31);
        *reinterpret_cast<bf16x8*>(&kb2[chunk * 8]) = val;
      }
    }
  } else {
    #pragma unroll
    for (int ni = 0; ni < 4; ++ni) {
      const float bz = bias[bcol + wc * 64 + ni * 16 + l16];
      #pragma unroll
      for (int mi = 0; mi < 4; ++mi) {
        f32x4 v = acc[mi][ni];
        #pragma unroll
        for (int j = 0; j < 4; ++j)
          T[(ni * 16 + l16) * 80 + mi * 16 + g * 4 + j] = f2b(v[j] + bz);
      }
    }
    const int h = (bcol + wc * 64) >> 6;
    const int m0 = brow + wr * 64;
    const int bb = m0 >> 10;
    const int kt = (m0 & 1023) >> 6;
    u16* vb = &Vf[(((size_t)(bb * 16 + h)) * 16 + kt) * 4096];
    #pragma unroll
    for (int it = 0; it < 8; ++it) {
      const int d = it * 8 + (lane >> 3);
      const int m8 = (lane & 7) * 8;
      bf16x8 val = *reinterpret_cast<const bf16x8*>(&T[d * 80 + m8]);
      const int chunk = (m8 >> 4) * 128 + (d >> 5) * 64 + ((m8 >> 3) & 1) * 32 + (d & 31);
      *reinterpret_cast<bf16x8*>(&vb[chunk * 8]) = val;
    }
  }
}

// ---- output projection: fp32 out ----
__global__ __launch_bounds__(256, 2) void gemm_o(const u16* __restrict__ A, const u16* __restrict__ Wt,
                                                 const float* __restrict__ bias, float* __restrict__ outp) {
  __shared__ u16 smem[32768];
  const int brow = blockIdx.x * 128, bcol = blockIdx.y * 128;
  f32x4 acc[4][4] = {};
  gemm_core(A, Wt, acc, brow, bcol, smem);
  const int lane = threadIdx.x & 63;
  const int w = threadIdx.x >> 6;
  const int wr = w >> 1, wc = w & 1;
  const int l16 = lane & 15, g = lane >> 4;
  #pragma unroll
  for (int ni = 0; ni < 4; ++ni) {
    const int col = bcol + wc * 64 + ni * 16 + l16;
    const float bz = bias[col];
    #pragma unroll
    for (int mi = 0; mi < 4; ++mi) {
      const int r0 = brow + wr * 64 + mi * 16 + g * 4;
      f32x4 v = acc[mi][ni];
      #pragma unroll
      for (int j = 0; j < 4; ++j) outp[(size_t)(r0 + j) * 1024 + col] = v[j] + bz;
    }
  }
}

// ---- flash attention (R11 proven form): 256 q-rows/block (8 waves x 32),
// fragment-order K/V staged in LDS, one barrier per kt ----
__global__ __launch_bounds__(512, 4) void attn2(const u16* __restrict__ Q, const u16* __restrict__ Kf,
                                                const u16* __restrict__ Vf, u16* __restrict__ AO) {
  __shared__ u16 Ks[2][64 * 64];
  __shared__ u16 Vs[2][64 * 64];
  const int tid = threadIdx.x, lane = tid & 63, w = tid >> 6;  // w: 0..7
  const int l32 = lane & 31, u = lane >> 5;
  // XCD-bijective swizzle: 512 blocks, 8 XCDs -> XCD x owns 64 contiguous ids
  // = 16 contiguous (b,h) pairs -> L2-local K/V.
  const int id = blockIdx.x;
  const int v = (id & 7) * 64 + (id >> 3);
  const int qt = v & 3, h = (v >> 2) & 15, b = v >> 6;
  const int q0 = qt * 256 + w * 32;

  bf16x8 qf[4];
  {
    const u16* qp = &Q[(size_t)(b * 1024 + q0 + l32) * 1024 + h * 64 + u * 8];
    #pragma unroll
    for (int m = 0; m < 4; ++m) qf[m] = *reinterpret_cast<const bf16x8*>(qp + m * 16);
  }

  f32x16 o0 = {}, o1 = {};
  float lr = 0.f;

  const u16* Kbh = Kf + (size_t)(b * 16 + h) * 65536;
  const u16* Vbh = Vf + (size_t)(b * 16 + h) * 65536;

  // 512 threads x 16B = one full 8KB tile each for K and V per call
  auto stage = [&](int buf, int kt) {
    const int c = tid * 8;
    gload_lds16(&Kbh[kt * 4096 + c], &Ks[buf][(w * 64) * 8]);
    gload_lds16(&Vbh[kt * 4096 + c], &Vs[buf][(w * 64) * 8]);
  };

  stage(0, 0);
  __syncthreads();
  int cur = 0;

  for (int kt = 0; kt < 16; ++kt) {
    if (kt < 15) stage(cur ^ 1, kt + 1);

    f32x16 s0 = {}, s1 = {};
    __builtin_amdgcn_s_setprio(1);
    #pragma unroll
    for (int m = 0; m < 4; ++m) {
      bf16x8 k0 = *reinterpret_cast<const bf16x8*>(&Ks[cur][m * 1024 + lane * 8]);
      bf16x8 k1 = *reinterpret_cast<const bf16x8*>(&Ks[cur][m * 1024 + 512 + lane * 8]);
      s0 = MFMA32(k0, qf[m], s0, 0, 0, 0);
      s1 = MFMA32(k1, qf[m], s1, 0, 0, 0);
    }
    __builtin_amdgcn_s_setprio(0);

    unsigned W0[8], W1[8];
    #pragma unroll
    for (int j = 0; j < 8; ++j) {
      const int r = 4 * (j >> 1) + 2 * (j & 1);
      float pa0 = __builtin_amdgcn_exp2f(s0[r]);
      float pb0 = __builtin_amdgcn_exp2f(s0[r + 1]);
      float pa1 = __builtin_amdgcn_exp2f(s1[r]);
      float pb1 = __builtin_amdgcn_exp2f(s1[r + 1]);
      lr += (pa0 + pb0) + (pa1 + pb1);
      asm("v_cvt_pk_bf16_f32 %0, %1, %2" : "=v"(W0[j]) : "v"(pa0), "v"(pb0));
      asm("v_cvt_pk_bf16_f32 %0, %1, %2" : "=v"(W1[j]) : "v"(pa1), "v"(pb1));
    }

    unsigned paw[4][4];
    #pragma unroll
    for (int ks = 0; ks < 4; ++ks) {
      const int ksl = ks & 1;
      #pragma unroll
      for (int p = 0; p < 2; ++p) {
        unsigned x = (ks < 2) ? W0[4 * ksl + p] : W1[4 * ksl + p];
        unsigned y = (ks < 2) ? W0[4 * ksl + 2 + p] : W1[4 * ksl + 2 + p];
        asm("v_permlane32_swap_b32 %0, %1" : "+v"(x), "+v"(y));
        paw[ks][p] = x;
        paw[ks][2 + p] = y;
      }
    }

    __builtin_amdgcn_s_setprio(1);
    #pragma unroll
    for (int ks = 0; ks < 4; ++ks) {
      bf16x8 pa = __builtin_bit_cast(bf16x8, u32x4{paw[ks][0], paw[ks][1], paw[ks][2], paw[ks][3]});
      bf16x8 v0 = *reinterpret_cast<const bf16x8*>(&Vs[cur][ks * 1024 + lane * 8]);
      bf16x8 v1 = *reinterpret_cast<const bf16x8*>(&Vs[cur][ks * 1024 + 512 + lane * 8]);
      o0 = MFMA32(pa, v0, o0, 0, 0, 0);
      o1 = MFMA32(pa, v1, o1, 0, 0, 0);
    }
    __builtin_amdgcn_s_setprio(0);

    __syncthreads();
    cur ^= 1;
  }

  float sum = lr + __shfl_xor(lr, 32);
  float rinv = 1.0f / sum;
  u16* aop = &AO[(size_t)(b * 1024 + q0) * 1024 + h * 64 + l32];
  #pragma unroll
  for (int r = 0; r < 16; ++r) {
    const int ql = (r & 3) + 8 * (r >> 2) + 4 * u;
    int ri_i = __builtin_amdgcn_ds_bpermute((ql + (u << 5)) << 2, __builtin_bit_cast(int, rinv));
    float ri = __builtin_bit_cast(float, ri_i);
    aop[(size_t)ql * 1024] = f2b(o0[r] * ri);
    aop[(size_t)ql * 1024 + 32] = f2b(o1[r] * ri);
  }
}

extern "C" void kernel_launch(void* const* d_in, const int* in_sizes, int n_in,
                              void* d_out, int out_size, void* d_ws, size_t ws_size,
                              hipStream_t stream) {
  const float* x   = (const float*)d_in[0];
  const float* ctx = (const float*)d_in[1];
  const float* Wq  = (const float*)d_in[2];
  const float* bq  = (const float*)d_in[3];
  const float* Wk  = (const float*)d_in[4];
  const float* bk  = (const float*)d_in[5];
  const float* Wv  = (const float*)d_in[6];
  const float* bv  = (const float*)d_in[7];
  const float* Wo  = (const float*)d_in[8];
  const float* bo  = (const float*)d_in[9];
  float* out = (float*)d_out;
  char* ws = (char*)d_ws;

  u16* xb  = (u16*)(ws + (size_t)0);          // 16MB (also reused as AO)
  u16* cb  = (u16*)(ws + ((size_t)16 << 20));
  u16* Qb  = (u16*)(ws + ((size_t)32 << 20));
  u16* Kf  = (u16*)(ws + ((size_t)48 << 20));
  u16* Vf  = (u16*)(ws + ((size_t)64 << 20));
  u16* Wqt = (u16*)(ws + ((size_t)80 << 20));
  u16* Wkt = (u16*)(ws + ((size_t)82 << 20));
  u16* Wvt = (u16*)(ws + ((size_t)84 << 20));
  u16* Wot = (u16*)(ws + ((size_t)86 << 20));

  prep<<<dim3(8192, 1, 3), 256, 0, stream>>>(x, ctx, xb, cb, Wq, Wk, Wv, Wo, Wqt, Wkt, Wvt, Wot);
  gemm_qkv<<<dim3(64, 8, 3), 256, 0, stream>>>(xb, cb, Wqt, Wkt, Wvt, bq, bk, bv, Qb, Kf, Vf);
  attn2<<<dim3(512), 512, 0, stream>>>(Qb, Kf, Vf, xb /*AO*/);
  gemm_o<<<dim3(64, 8), 256, 0, stream>>>(xb, Wot, bo, out);
}